// Round 7
// baseline (197.130 us; speedup 1.0000x reference)
//
#include <hip/hip_runtime.h>
#include <hip/hip_bf16.h>

#define EPS 1e-8f
#define B_  16
#define CIN 256
#define COUT 256
#define HW 64

typedef __bf16 bf16x8 __attribute__((ext_vector_type(8)));
typedef float  f32x4  __attribute__((ext_vector_type(4)));

__device__ __forceinline__ void async16(void* lds, const void* g) {
    __builtin_amdgcn_global_load_lds(
        (const __attribute__((address_space(1))) unsigned int*)g,
        (__attribute__((address_space(3))) unsigned int*)lds,
        16, 0, 0);
}
// NT variant: aux=2 (SLC/NT on gfx950) — xbf is streamed, keep it from evicting wfull in L2.
__device__ __forceinline__ void async16nt(void* lds, const void* g) {
    __builtin_amdgcn_global_load_lds(
        (const __attribute__((address_space(1))) unsigned int*)g,
        (__attribute__((address_space(3))) unsigned int*)lds,
        16, 0, 2);
}

__device__ __forceinline__ uint pack2(float lo, float hi) {
    __bf16 a = (__bf16)lo, b = (__bf16)hi;
    unsigned short ua = __builtin_bit_cast(unsigned short, a);
    unsigned short ub = __builtin_bit_cast(unsigned short, b);
    return ((uint)ub << 16) | (uint)ua;
}

// ================= fused prep kernel (role-ordered, unchanged from r6) =================
// bid 0..1023   : x transpose role (row = bid&63, b = bid>>6)
// bid 1024      : zrow zero-fill
// bid 1025..1280: wmod role (co = bid-1025), launches last -> wfull freshest in L2
__global__ __launch_bounds__(256) void prep_kernel(const float* __restrict__ x,
                                                   const float* __restrict__ s,
                                                   const float* __restrict__ w,
                                                   __bf16* __restrict__ xbf,
                                                   __bf16* __restrict__ wfull,
                                                   __bf16* __restrict__ zrow) {
    __shared__ uint xsd[64 * 160];
    __shared__ float red[8];
    const int bid = blockIdx.x;
    const int t   = threadIdx.x;

    if (bid == 1024) {
        uint4 z = make_uint4(0, 0, 0, 0);
        uint4* zp = (uint4*)zrow;
#pragma unroll
        for (int k = 0; k < 9; ++k) zp[k * 256 + t] = z;
        return;
    }

    if (bid > 1024) {                 // ---- wmod role ----
        const int co = bid - 1025;
        const int ci = t;
        const int lane = t & 63, wid = t >> 6;
        float as = 0.f;
#pragma unroll
        for (int k = 0; k < 16; ++k) { float sv = s[k * 256 + t]; as += sv * sv; }
        const float* wp = w + ((size_t)co * CIN + ci) * 9;
        float wv[9];
        float q = 0.f;
#pragma unroll
        for (int tp = 0; tp < 9; ++tp) { wv[tp] = wp[tp]; q += wv[tp] * wv[tp]; }
        float a = as, qq = q;
        for (int off = 32; off > 0; off >>= 1) {
            a  += __shfl_down(a,  off, 64);
            qq += __shfl_down(qq, off, 64);
        }
        if (lane == 0) { red[wid] = a; red[4 + wid] = qq; }
        __syncthreads();
        const float ssum = red[0] + red[1] + red[2] + red[3];
        const float Sw   = red[4] + red[5] + red[6] + red[7];
        const float sn2  = (float)(B_ * CIN) / ssum;
        const float wn   = rsqrtf(Sw / 2304.f);
        const float wn2sn2 = wn * wn * sn2;
        const float wsn  = wn * sqrtf(sn2);

        for (int b = 0; b < B_; ++b) {
            const float sv = s[b * CIN + ci];
            float v = sv * sv * q;
            for (int off = 32; off > 0; off >>= 1) v += __shfl_down(v, off, 64);
            __syncthreads();
            if (lane == 0) red[wid] = v;
            __syncthreads();
            const float S = red[0] + red[1] + red[2] + red[3];
            const float coef = wsn * rsqrtf(wn2sn2 * S + EPS);
            const float sc = sv * coef;
            const size_t obase = ((size_t)b * 9) * 65536 + (size_t)(ci >> 5) * 8192
                               + (size_t)co * 32 + (ci & 31);
#pragma unroll
            for (int tap = 0; tap < 9; ++tap)
                wfull[obase + (size_t)tap * 65536] = (__bf16)(wv[tap] * sc);
        }
        return;
    }

    // ---- x transpose role ----
    const int row = bid & 63;
    const int b   = bid >> 6;
    const float* xbase = x + ((size_t)b * CIN * HW + row) * HW;
#pragma unroll
    for (int k = 0; k < 8; ++k) {
        int p   = k * 256 + t;
        int ci2 = p >> 4;
        int c4  = (p & 15) * 4;
        const float* src = xbase + (size_t)(2 * ci2) * (HW * HW) + c4;
        float4 v0 = *(const float4*)src;
        float4 v1 = *(const float4*)(src + HW * HW);
        const int dj = ci2 + (ci2 >> 2);
#pragma unroll
        for (int i = 0; i < 4; ++i)
            xsd[(c4 + i) * 160 + dj] = pack2((&v0.x)[i], (&v1.x)[i]);
    }
    __syncthreads();
    __bf16* orow = xbf + (((size_t)b * HW + row) * 64) * CIN;
#pragma unroll
    for (int k = 0; k < 8; ++k) {
        int o   = k * 256 + t;
        int col = o >> 5;
        int u   = o & 31;
        const uint* rp = &xsd[col * 160 + 5 * u];
        uint4 vv; vv.x = rp[0]; vv.y = rp[1]; vv.z = rp[2]; vv.w = rp[3];
        *(uint4*)&orow[(size_t)col * CIN + u * 8] = vv;
    }
}

// ================= MFMA implicit-GEMM conv, v9 =================
// v8 (2-row blocks, grid 512, acc[4][8]) +
//  (a) q-stride 264 -> 266 slots: 4256 B === 32 mod 128 -> q-groups 8 banks apart,
//      kills the deterministic 4-way conflict on every ds_read_b128.
//  (b) j-outer MFMA order + B-prefetch of bfr[0..3] one tap ahead (pb/nb rotation):
//      tap's first 16 MFMAs consume prefetched frags, no per-tap lgkm stall at
//      2 waves/SIMD. j4..7 loaded in-tap (first use >=16 MFMAs in).
//  (c) NT policy: xbf staging aux=2, out stores nontemporal -> wfull (2.3 MB/XCD,
//      32x reuse) stays L2-resident instead of being evicted by streams.
// LDS per buf: 4 q-groups x 266 slots of 16B (slots 0..263 used; 264/265 pad).
__global__ __launch_bounds__(256, 2) void conv_mfma5(const __bf16* __restrict__ xbf,
                                                     const __bf16* __restrict__ zrow,
                                                     const __bf16* __restrict__ wfull,
                                                     float* __restrict__ out) {
    __shared__ __attribute__((aligned(16))) __bf16 xs[2][1064 * 8];   // 2 x 17,024 B

    const int bid = blockIdx.x;
    const int b   = (bid & 7) + ((bid >= 256) ? 8 : 0);
    const int r0  = ((bid >> 3) & 31) * 2;
    const int t = threadIdx.x;
    const int wy = t >> 6, lane = t & 63;
    const int m16 = lane & 15, q = lane >> 4;

    // staging sources: issues 0..3: (qq=i, rem=t); issue 4: (qq=wy, rem=256+lane), lane<8
    const __bf16* gsrc[5];
#pragma unroll
    for (int i = 0; i < 5; ++i) {
        int qq, rem;
        if (i < 4) { qq = i;  rem = t; }
        else       { qq = wy; rem = 256 + (lane & 7); }
        int irow = rem / 66;
        int col  = rem - irow * 66;
        int gr   = r0 - 1 + irow;
        if ((unsigned)gr < 64u && col != 0 && col != 65)
            gsrc[i] = xbf + (((size_t)b * HW + gr) * 64 + (col - 1)) * CIN + qq * 8;
        else
            gsrc[i] = zrow + col * CIN + qq * 8;    // zero halo pool
    }

    // prologue: stage chunk 0 into buf 0
#pragma unroll
    for (int i = 0; i < 4; ++i)
        async16nt((char*)xs[0] + (i * 266 + t) * 16, gsrc[i]);
    if (lane < 8)
        async16nt((char*)xs[0] + (wy * 266 + 256 + lane) * 16, gsrc[4]);

    f32x4 acc[4][8] = {};
    const __bf16* abase = wfull + (size_t)b * 589824
                        + (size_t)(wy * 64 + m16) * 32 + q * 8;

    // B slot address helper values (compile-time per unrolled tap/j):
    //   slot(tap, j) = q*266 + ((j>>2) + tap/3)*66 + (j&3)*16 + m16 + tap%3
    const int sbase = q * 266 + m16;

    for (int cc = 0; cc < 8; ++cc) {
        const __bf16* wb = abase + (size_t)cc * 8192;
        __syncthreads();                       // drains chunk-cc staging
        if (cc < 7) {
            const int d = cc * 32 + 32;
#pragma unroll
            for (int i = 0; i < 4; ++i)
                async16nt((char*)xs[(cc + 1) & 1] + (i * 266 + t) * 16, gsrc[i] + d);
            if (lane < 8)
                async16nt((char*)xs[(cc + 1) & 1] + (wy * 266 + 256 + lane) * 16, gsrc[4] + d);
        }
        const __bf16* xcur = xs[cc & 1];

        // cc-start loads: A tap0 + prefetched B j0..3 of tap0
        bf16x8 afc[4], pb[4];
#pragma unroll
        for (int i = 0; i < 4; ++i)
            afc[i] = *(const bf16x8*)(wb + i * 512);
#pragma unroll
        for (int j = 0; j < 4; ++j)
            pb[j] = *(const bf16x8*)&xcur[(sbase + j * 16) * 8];

#pragma unroll
        for (int tap = 0; tap < 9; ++tap) {
            const int dr = tap / 3, dc = tap % 3;
            // in-tap loads: current tap j4..7
            bf16x8 cur[4];
#pragma unroll
            for (int j = 0; j < 4; ++j)
                cur[j] = *(const bf16x8*)&xcur[(sbase + (1 + dr) * 66 + j * 16 + dc) * 8];
            // prefetch next tap's j0..3 and next A
            bf16x8 nb[4], afn[4];
            if (tap < 8) {
                const int ndr = (tap + 1) / 3, ndc = (tap + 1) % 3;
#pragma unroll
                for (int j = 0; j < 4; ++j)
                    nb[j] = *(const bf16x8*)&xcur[(sbase + ndr * 66 + j * 16 + ndc) * 8];
#pragma unroll
                for (int i = 0; i < 4; ++i)
                    afn[i] = *(const bf16x8*)(wb + (size_t)(tap + 1) * 65536 + i * 512);
            }
            __builtin_amdgcn_s_setprio(1);
#pragma unroll
            for (int j = 0; j < 4; ++j)
#pragma unroll
                for (int i = 0; i < 4; ++i)
                    acc[i][j] = __builtin_amdgcn_mfma_f32_16x16x32_bf16(afc[i], pb[j], acc[i][j], 0, 0, 0);
#pragma unroll
            for (int j = 0; j < 4; ++j)
#pragma unroll
                for (int i = 0; i < 4; ++i)
                    acc[i][4 + j] = __builtin_amdgcn_mfma_f32_16x16x32_bf16(afc[i], cur[j], acc[i][4 + j], 0, 0, 0);
            __builtin_amdgcn_s_setprio(0);
            if (tap < 8) {
#pragma unroll
                for (int j = 0; j < 4; ++j) pb[j] = nb[j];
#pragma unroll
                for (int i = 0; i < 4; ++i) afc[i] = afn[i];
            }
        }
    }

    // epilogue: nontemporal stores (out is write-once) — keep L2 for wfull.
    // tile j: out row = r0 + (j>>2), cols (j&3)*16 + m16; acc row = q*4+reg (co)
#pragma unroll
    for (int i = 0; i < 4; ++i) {
        const int cobase = wy * 64 + i * 16 + q * 4;
#pragma unroll
        for (int reg = 0; reg < 4; ++reg) {
            float* op = out + ((size_t)b * COUT + (cobase + reg)) * (HW * HW) + r0 * HW + m16;
#pragma unroll
            for (int j = 0; j < 8; ++j)
                __builtin_nontemporal_store(acc[i][j][reg], op + (j >> 2) * HW + (j & 3) * 16);
        }
    }
}

extern "C" void kernel_launch(void* const* d_in, const int* in_sizes, int n_in,
                              void* d_out, int out_size, void* d_ws, size_t ws_size,
                              hipStream_t stream) {
    const float* x = (const float*)d_in[0];
    const float* s = (const float*)d_in[1];
    const float* w = (const float*)d_in[2];
    float* out = (float*)d_out;

    float* ws = (float*)d_ws;
    __bf16* wfull = (__bf16*)(ws + 70656);     // 18,874,368 B
    __bf16* zrow  = (__bf16*)(ws + 4789248);   // 36,864 B zero pool
    __bf16* xbf   = (__bf16*)(ws + 4798464);   // 33,554,432 B

    prep_kernel<<<1281, 256, 0, stream>>>(x, s, w, xbf, wfull, zrow);
    conv_mfma5<<<512, 256, 0, stream>>>(xbf, zrow, wfull, out);
}

// Round 8
// 195.747 us; speedup vs baseline: 1.0071x; 1.0071x over previous
//
#include <hip/hip_runtime.h>
#include <hip/hip_bf16.h>

#define EPS 1e-8f
#define B_  16
#define CIN 256
#define COUT 256
#define HW 64

typedef __bf16 bf16x8 __attribute__((ext_vector_type(8)));
typedef float  f32x4  __attribute__((ext_vector_type(4)));

__device__ __forceinline__ void async16(void* lds, const void* g) {
    __builtin_amdgcn_global_load_lds(
        (const __attribute__((address_space(1))) unsigned int*)g,
        (__attribute__((address_space(3))) unsigned int*)lds,
        16, 0, 0);
}

__device__ __forceinline__ uint pack2(float lo, float hi) {
    __bf16 a = (__bf16)lo, b = (__bf16)hi;
    unsigned short ua = __builtin_bit_cast(unsigned short, a);
    unsigned short ub = __builtin_bit_cast(unsigned short, b);
    return ((uint)ub << 16) | (uint)ua;
}

// ================= fused prep kernel (role-ordered) =================
// bid 0..1023   : x transpose role (row = bid&63, b = bid>>6)
// bid 1024      : zrow zero-fill
// bid 1025..1280: wmod role (co = bid-1025), launches last -> wfull freshest in L2
// wfull layout: [b][tap][cc=ci>>5][co][ci&31]  (conv A-frag = one contiguous 1 KB)
// xbf layout:   [b][row][col 0..63][ci]  (bf16, no halo cols)
__global__ __launch_bounds__(256) void prep_kernel(const float* __restrict__ x,
                                                   const float* __restrict__ s,
                                                   const float* __restrict__ w,
                                                   __bf16* __restrict__ xbf,
                                                   __bf16* __restrict__ wfull,
                                                   __bf16* __restrict__ zrow) {
    // transpose LDS: stride 165 dwords (was 160 == 0 mod 32 -> 16-way write
    // conflict; 165*4 = 660 == 20 mod 32 -> 8 banks x 2 lanes = free).
    __shared__ uint xsd[64 * 165];   // 42,240 B
    __shared__ float red[8];
    const int bid = blockIdx.x;
    const int t   = threadIdx.x;

    if (bid == 1024) {
        uint4 z = make_uint4(0, 0, 0, 0);
        uint4* zp = (uint4*)zrow;
#pragma unroll
        for (int k = 0; k < 9; ++k) zp[k * 256 + t] = z;
        return;
    }

    if (bid > 1024) {                 // ---- wmod role ----
        const int co = bid - 1025;
        const int ci = t;
        const int lane = t & 63, wid = t >> 6;
        float as = 0.f;
#pragma unroll
        for (int k = 0; k < 16; ++k) { float sv = s[k * 256 + t]; as += sv * sv; }
        const float* wp = w + ((size_t)co * CIN + ci) * 9;
        float wv[9];
        float q = 0.f;
#pragma unroll
        for (int tp = 0; tp < 9; ++tp) { wv[tp] = wp[tp]; q += wv[tp] * wv[tp]; }
        float a = as, qq = q;
        for (int off = 32; off > 0; off >>= 1) {
            a  += __shfl_down(a,  off, 64);
            qq += __shfl_down(qq, off, 64);
        }
        if (lane == 0) { red[wid] = a; red[4 + wid] = qq; }
        __syncthreads();
        const float ssum = red[0] + red[1] + red[2] + red[3];
        const float Sw   = red[4] + red[5] + red[6] + red[7];
        const float sn2  = (float)(B_ * CIN) / ssum;
        const float wn   = rsqrtf(Sw / 2304.f);
        const float wn2sn2 = wn * wn * sn2;
        const float wsn  = wn * sqrtf(sn2);

        for (int b = 0; b < B_; ++b) {
            const float sv = s[b * CIN + ci];
            float v = sv * sv * q;
            for (int off = 32; off > 0; off >>= 1) v += __shfl_down(v, off, 64);
            __syncthreads();
            if (lane == 0) red[wid] = v;
            __syncthreads();
            const float S = red[0] + red[1] + red[2] + red[3];
            const float coef = wsn * rsqrtf(wn2sn2 * S + EPS);
            const float sc = sv * coef;
            const size_t obase = ((size_t)b * 9) * 65536 + (size_t)(ci >> 5) * 8192
                               + (size_t)co * 32 + (ci & 31);
#pragma unroll
            for (int tap = 0; tap < 9; ++tap)
                wfull[obase + (size_t)tap * 65536] = (__bf16)(wv[tap] * sc);
        }
        return;
    }

    // ---- x transpose role: fp32 NCHW -> bf16 [b][row][col][ci] ----
    const int row = bid & 63;
    const int b   = bid >> 6;
    const float* xbase = x + ((size_t)b * CIN * HW + row) * HW;
#pragma unroll
    for (int k = 0; k < 8; ++k) {
        int p   = k * 256 + t;
        int ci2 = p >> 4;
        int c4  = (p & 15) * 4;
        const float* src = xbase + (size_t)(2 * ci2) * (HW * HW) + c4;
        float4 v0 = *(const float4*)src;
        float4 v1 = *(const float4*)(src + HW * HW);
        const int dj = ci2 + (ci2 >> 2);
#pragma unroll
        for (int i = 0; i < 4; ++i)
            xsd[(c4 + i) * 165 + dj] = pack2((&v0.x)[i], (&v1.x)[i]);
    }
    __syncthreads();
    __bf16* orow = xbf + (((size_t)b * HW + row) * 64) * CIN;
#pragma unroll
    for (int k = 0; k < 8; ++k) {
        int o   = k * 256 + t;
        int col = o >> 5;
        int u   = o & 31;
        const uint* rp = &xsd[col * 165 + 5 * u];
        uint4 vv; vv.x = rp[0]; vv.y = rp[1]; vv.z = rp[2]; vv.w = rp[3];
        *(uint4*)&orow[(size_t)col * CIN + u * 8] = vv;
    }
}

// ================= MFMA implicit-GEMM conv, v10 = v8 + XOR slot swizzle =================
// grid 512 (XCD-affine: b = (bid&7)+8*(bid>=256), rowpair = (bid>>3)&31), 4 waves.
// Each block: 2 output rows (128 px) x 256 co; wave wy = co quarter, acc[4][8].
// LDS x tile (per buf): 4 q-groups x 264 slots of 16B.
//   Physical slot for logical (qq, rem) = qq*264 + (rem ^ qq)  [v6-proven swizzle:
//   the low-2-bit XOR breaks the lane-order bank aliasing that slot-granular
//   padding provably cannot (strides 200/264/266 all measured 4 conflicts/read;
//   XOR measured 1.33/read)]. Staging keeps LINEAR dest (global_load_lds) and
//   pre-swizzles the GLOBAL source: dest slot qq*264+t  <=>  rem = t ^ qq.
__global__ __launch_bounds__(256, 2) void conv_mfma6(const __bf16* __restrict__ xbf,
                                                     const __bf16* __restrict__ zrow,
                                                     const __bf16* __restrict__ wfull,
                                                     float* __restrict__ out) {
    __shared__ __attribute__((aligned(16))) __bf16 xs[2][1056 * 8];   // 2 x 16,896 B

    const int bid = blockIdx.x;
    const int b   = (bid & 7) + ((bid >= 256) ? 8 : 0);
    const int r0  = ((bid >> 3) & 31) * 2;
    const int t = threadIdx.x;
    const int wy = t >> 6, lane = t & 63;
    const int m16 = lane & 15, q = lane >> 4;

    // staging sources: issues 0..3: dest slot i*264+t -> logical rem = t^i, qq=i;
    // issue 4: dest slot wy*264+256+lane (lane<8) -> rem = 256 + (lane^wy), qq=wy.
    const __bf16* gsrc[5];
#pragma unroll
    for (int i = 0; i < 5; ++i) {
        int qq, rem;
        if (i < 4) { qq = i;  rem = t ^ i; }
        else       { qq = wy; rem = 256 + ((lane & 7) ^ wy); }
        int irow = rem / 66;
        int col  = rem - irow * 66;
        int gr   = r0 - 1 + irow;
        if ((unsigned)gr < 64u && col != 0 && col != 65)
            gsrc[i] = xbf + (((size_t)b * HW + gr) * 64 + (col - 1)) * CIN + qq * 8;
        else
            gsrc[i] = zrow + col * CIN + qq * 8;    // zero halo pool
    }

    // prologue: stage chunk 0 into buf 0
#pragma unroll
    for (int i = 0; i < 4; ++i)
        async16((char*)xs[0] + (i * 264 + t) * 16, gsrc[i]);
    if (lane < 8)
        async16((char*)xs[0] + (wy * 264 + 256 + lane) * 16, gsrc[4]);

    f32x4 acc[4][8] = {};
    const __bf16* abase = wfull + (size_t)b * 589824
                        + (size_t)(wy * 64 + m16) * 32 + q * 8;

    bf16x8 afc[4];
#pragma unroll
    for (int i = 0; i < 4; ++i)
        afc[i] = *(const bf16x8*)(abase + i * 512);    // cc=0, tap=0

    for (int cc = 0; cc < 8; ++cc) {
        const __bf16* wb = abase + (size_t)cc * 8192;
        __syncthreads();                       // drains chunk-cc staging
        if (cc < 7) {
            const int d = cc * 32 + 32;
#pragma unroll
            for (int i = 0; i < 4; ++i)
                async16((char*)xs[(cc + 1) & 1] + (i * 264 + t) * 16, gsrc[i] + d);
            if (lane < 8)
                async16((char*)xs[(cc + 1) & 1] + (wy * 264 + 256 + lane) * 16, gsrc[4] + d);
        }
        const __bf16* xcur = xs[cc & 1];
#pragma unroll
        for (int tap = 0; tap < 9; ++tap) {
            const int dr = tap / 3, dc = tap % 3;
            bf16x8 bfr[8];
#pragma unroll
            for (int j = 0; j < 8; ++j) {
                const int rem  = ((j >> 2) + dr) * 66 + (j & 3) * 16 + m16 + dc;
                const int slot = q * 264 + (rem ^ q);
                bfr[j] = *(const bf16x8*)&xcur[slot * 8];
            }
            bf16x8 afn[4];
            if (tap < 8) {
#pragma unroll
                for (int i = 0; i < 4; ++i)
                    afn[i] = *(const bf16x8*)(wb + (size_t)(tap + 1) * 65536 + i * 512);
            } else if (cc < 7) {
#pragma unroll
                for (int i = 0; i < 4; ++i)
                    afn[i] = *(const bf16x8*)(wb + 8192 + i * 512);
            }
            __builtin_amdgcn_s_setprio(1);
#pragma unroll
            for (int i = 0; i < 4; ++i)
#pragma unroll
                for (int j = 0; j < 8; ++j)
                    acc[i][j] = __builtin_amdgcn_mfma_f32_16x16x32_bf16(afc[i], bfr[j], acc[i][j], 0, 0, 0);
            __builtin_amdgcn_s_setprio(0);
            if (tap < 8 || cc < 7) {
#pragma unroll
                for (int i = 0; i < 4; ++i) afc[i] = afn[i];
            }
        }
    }

    // epilogue: D col = lane&15 (pixel within 16), row = q*4+reg (co)
    // tile j: out row = r0 + (j>>2), cols (j&3)*16 + m16
#pragma unroll
    for (int i = 0; i < 4; ++i) {
        const int cobase = wy * 64 + i * 16 + q * 4;
#pragma unroll
        for (int reg = 0; reg < 4; ++reg) {
            float* op = out + ((size_t)b * COUT + (cobase + reg)) * (HW * HW) + r0 * HW + m16;
#pragma unroll
            for (int j = 0; j < 8; ++j)
                op[(j >> 2) * HW + (j & 3) * 16] = acc[i][j][reg];
        }
    }
}

extern "C" void kernel_launch(void* const* d_in, const int* in_sizes, int n_in,
                              void* d_out, int out_size, void* d_ws, size_t ws_size,
                              hipStream_t stream) {
    const float* x = (const float*)d_in[0];
    const float* s = (const float*)d_in[1];
    const float* w = (const float*)d_in[2];
    float* out = (float*)d_out;

    float* ws = (float*)d_ws;
    __bf16* wfull = (__bf16*)(ws + 70656);     // 18,874,368 B
    __bf16* zrow  = (__bf16*)(ws + 4789248);   // 36,864 B zero pool
    __bf16* xbf   = (__bf16*)(ws + 4798464);   // 33,554,432 B

    prep_kernel<<<1281, 256, 0, stream>>>(x, s, w, xbf, wfull, zrow);
    conv_mfma6<<<512, 256, 0, stream>>>(xbf, zrow, wfull, out);
}

// Round 9
// 183.142 us; speedup vs baseline: 1.0764x; 1.0688x over previous
//
#include <hip/hip_runtime.h>
#include <hip/hip_bf16.h>

#define EPS 1e-8f
#define B_  16
#define CIN 256
#define COUT 256
#define HW 64

typedef __bf16 bf16x8 __attribute__((ext_vector_type(8)));
typedef float  f32x4  __attribute__((ext_vector_type(4)));

__device__ __forceinline__ void async16(void* lds, const void* g) {
    __builtin_amdgcn_global_load_lds(
        (const __attribute__((address_space(1))) unsigned int*)g,
        (__attribute__((address_space(3))) unsigned int*)lds,
        16, 0, 0);
}

__device__ __forceinline__ uint pack2(float lo, float hi) {
    __bf16 a = (__bf16)lo, b = (__bf16)hi;
    unsigned short ua = __builtin_bit_cast(unsigned short, a);
    unsigned short ub = __builtin_bit_cast(unsigned short, b);
    return ((uint)ub << 16) | (uint)ua;
}

// ================= fused prep kernel (role-ordered) =================
// bid 0..1023   : x transpose role (row = bid&63, b = bid>>6)
// bid 1024      : zrow zero-fill
// bid 1025..1280: wmod role (co = bid-1025), launches last -> wfull freshest in L2
// wfull layout: [b][tap][cc=ci>>5][co][ci&31]  (conv A-frag = one contiguous 1 KB)
// xbf layout:   [b][row][col 0..63][ci]  (bf16, no halo cols)
__global__ __launch_bounds__(256) void prep_kernel(const float* __restrict__ x,
                                                   const float* __restrict__ s,
                                                   const float* __restrict__ w,
                                                   __bf16* __restrict__ xbf,
                                                   __bf16* __restrict__ wfull,
                                                   __bf16* __restrict__ zrow) {
    // transpose LDS stride S=159 dwords:
    //  - writes: lane group stride 4*S*4B = 2544B === 112 mod 128 -> 8 banks x 2 lanes (free)
    //  - reads:  stride 5 dwords, coprime 32 -> conflict-free
    //  - skew max index 127 + 31 = 158 < 159 (fits)
    //  - footprint 64*159*4 = 40,704 B -> 4 blocks/CU (165 was 42,240 -> only 3/CU)
    __shared__ uint xsd[64 * 159];   // 40,704 B
    __shared__ float red[8];
    const int bid = blockIdx.x;
    const int t   = threadIdx.x;

    if (bid == 1024) {
        uint4 z = make_uint4(0, 0, 0, 0);
        uint4* zp = (uint4*)zrow;
#pragma unroll
        for (int k = 0; k < 9; ++k) zp[k * 256 + t] = z;
        return;
    }

    if (bid > 1024) {                 // ---- wmod role ----
        const int co = bid - 1025;
        const int ci = t;
        const int lane = t & 63, wid = t >> 6;
        float as = 0.f;
#pragma unroll
        for (int k = 0; k < 16; ++k) { float sv = s[k * 256 + t]; as += sv * sv; }
        const float* wp = w + ((size_t)co * CIN + ci) * 9;
        float wv[9];
        float q = 0.f;
#pragma unroll
        for (int tp = 0; tp < 9; ++tp) { wv[tp] = wp[tp]; q += wv[tp] * wv[tp]; }
        float a = as, qq = q;
        for (int off = 32; off > 0; off >>= 1) {
            a  += __shfl_down(a,  off, 64);
            qq += __shfl_down(qq, off, 64);
        }
        if (lane == 0) { red[wid] = a; red[4 + wid] = qq; }
        __syncthreads();
        const float ssum = red[0] + red[1] + red[2] + red[3];
        const float Sw   = red[4] + red[5] + red[6] + red[7];
        const float sn2  = (float)(B_ * CIN) / ssum;
        const float wn   = rsqrtf(Sw / 2304.f);
        const float wn2sn2 = wn * wn * sn2;
        const float wsn  = wn * sqrtf(sn2);

        for (int b = 0; b < B_; ++b) {
            const float sv = s[b * CIN + ci];
            float v = sv * sv * q;
            for (int off = 32; off > 0; off >>= 1) v += __shfl_down(v, off, 64);
            __syncthreads();
            if (lane == 0) red[wid] = v;
            __syncthreads();
            const float S = red[0] + red[1] + red[2] + red[3];
            const float coef = wsn * rsqrtf(wn2sn2 * S + EPS);
            const float sc = sv * coef;
            const size_t obase = ((size_t)b * 9) * 65536 + (size_t)(ci >> 5) * 8192
                               + (size_t)co * 32 + (ci & 31);
#pragma unroll
            for (int tap = 0; tap < 9; ++tap)
                wfull[obase + (size_t)tap * 65536] = (__bf16)(wv[tap] * sc);
        }
        return;
    }

    // ---- x transpose role: fp32 NCHW -> bf16 [b][row][col][ci] ----
    const int row = bid & 63;
    const int b   = bid >> 6;
    const float* xbase = x + ((size_t)b * CIN * HW + row) * HW;
#pragma unroll
    for (int k = 0; k < 8; ++k) {
        int p   = k * 256 + t;
        int ci2 = p >> 4;
        int c4  = (p & 15) * 4;
        const float* src = xbase + (size_t)(2 * ci2) * (HW * HW) + c4;
        float4 v0 = *(const float4*)src;
        float4 v1 = *(const float4*)(src + HW * HW);
        const int dj = ci2 + (ci2 >> 2);
#pragma unroll
        for (int i = 0; i < 4; ++i)
            xsd[(c4 + i) * 159 + dj] = pack2((&v0.x)[i], (&v1.x)[i]);
    }
    __syncthreads();
    __bf16* orow = xbf + (((size_t)b * HW + row) * 64) * CIN;
#pragma unroll
    for (int k = 0; k < 8; ++k) {
        int o   = k * 256 + t;
        int col = o >> 5;
        int u   = o & 31;
        const uint* rp = &xsd[col * 159 + 5 * u];
        uint4 vv; vv.x = rp[0]; vv.y = rp[1]; vv.z = rp[2]; vv.w = rp[3];
        *(uint4*)&orow[(size_t)col * CIN + u * 8] = vv;
    }
}

// ================= MFMA implicit-GEMM conv, v8 (reverted champion, 70 us) =================
// grid 512 (XCD-affine: b = (bid&7)+8*(bid>=256), rowpair = (bid>>3)&31), 4 waves.
// Each block: 2 output rows (128 px) x 256 co. Wave wy = co quarter:
// 64 co x 128 px via acc[4][8]. Per tap: 32 MFMA vs 4 A-loads + 8 B-reads.
// NOTE: SQ_LDS_BANK_CONFLICT = 4/b128-read is STRUCTURAL (m134: b128 = 12 cy vs
// 8 ideal) — invariant across strides 200/264/266/XOR. Do not chase it.
// LDS x tile (per buf): 4 qq x (4 halo rows x 66 cols) = 1056 slots of 16B;
// slot = qq*264 + irow*66 + col. Staged via 4 full async16 rounds + 8-lane tail.
__global__ __launch_bounds__(256, 2) void conv_mfma4(const __bf16* __restrict__ xbf,
                                                     const __bf16* __restrict__ zrow,
                                                     const __bf16* __restrict__ wfull,
                                                     float* __restrict__ out) {
    __shared__ __attribute__((aligned(16))) __bf16 xs[2][1056 * 8];   // 2 x 16,896 B

    const int bid = blockIdx.x;
    const int b   = (bid & 7) + ((bid >= 256) ? 8 : 0);
    const int r0  = ((bid >> 3) & 31) * 2;
    const int t = threadIdx.x;
    const int wy = t >> 6, lane = t & 63;
    const int m16 = lane & 15, q = lane >> 4;

    // staging sources: issues 0..3: (qq=i, rem=t); issue 4: (qq=wy, rem=256+lane), lane<8
    const __bf16* gsrc[5];
#pragma unroll
    for (int i = 0; i < 5; ++i) {
        int qq, rem;
        if (i < 4) { qq = i;  rem = t; }
        else       { qq = wy; rem = 256 + (lane & 7); }
        int irow = rem / 66;
        int col  = rem - irow * 66;
        int gr   = r0 - 1 + irow;
        if ((unsigned)gr < 64u && col != 0 && col != 65)
            gsrc[i] = xbf + (((size_t)b * HW + gr) * 64 + (col - 1)) * CIN + qq * 8;
        else
            gsrc[i] = zrow + col * CIN + qq * 8;    // zero halo pool
    }

    // prologue: stage chunk 0 into buf 0
#pragma unroll
    for (int i = 0; i < 4; ++i)
        async16((char*)xs[0] + (i * 264 + t) * 16, gsrc[i]);
    if (lane < 8)
        async16((char*)xs[0] + (wy * 264 + 256 + lane) * 16, gsrc[4]);

    f32x4 acc[4][8] = {};
    const __bf16* abase = wfull + (size_t)b * 589824
                        + (size_t)(wy * 64 + m16) * 32 + q * 8;

    bf16x8 afc[4];
#pragma unroll
    for (int i = 0; i < 4; ++i)
        afc[i] = *(const bf16x8*)(abase + i * 512);    // cc=0, tap=0

    for (int cc = 0; cc < 8; ++cc) {
        const __bf16* wb = abase + (size_t)cc * 8192;
        __syncthreads();                       // drains chunk-cc staging
        if (cc < 7) {
            const int d = cc * 32 + 32;
#pragma unroll
            for (int i = 0; i < 4; ++i)
                async16((char*)xs[(cc + 1) & 1] + (i * 264 + t) * 16, gsrc[i] + d);
            if (lane < 8)
                async16((char*)xs[(cc + 1) & 1] + (wy * 264 + 256 + lane) * 16, gsrc[4] + d);
        }
        const __bf16* xcur = xs[cc & 1];
#pragma unroll
        for (int tap = 0; tap < 9; ++tap) {
            const int dr = tap / 3, dc = tap % 3;
            bf16x8 bfr[8];
#pragma unroll
            for (int j = 0; j < 8; ++j) {
                const int slot = q * 264 + ((j >> 2) + dr) * 66 + (j & 3) * 16 + m16 + dc;
                bfr[j] = *(const bf16x8*)&xcur[slot * 8];
            }
            bf16x8 afn[4];
            if (tap < 8) {
#pragma unroll
                for (int i = 0; i < 4; ++i)
                    afn[i] = *(const bf16x8*)(wb + (size_t)(tap + 1) * 65536 + i * 512);
            } else if (cc < 7) {
#pragma unroll
                for (int i = 0; i < 4; ++i)
                    afn[i] = *(const bf16x8*)(wb + 8192 + i * 512);
            }
            __builtin_amdgcn_s_setprio(1);
#pragma unroll
            for (int i = 0; i < 4; ++i)
#pragma unroll
                for (int j = 0; j < 8; ++j)
                    acc[i][j] = __builtin_amdgcn_mfma_f32_16x16x32_bf16(afc[i], bfr[j], acc[i][j], 0, 0, 0);
            __builtin_amdgcn_s_setprio(0);
            if (tap < 8 || cc < 7) {
#pragma unroll
                for (int i = 0; i < 4; ++i) afc[i] = afn[i];
            }
        }
    }

    // epilogue: D col = lane&15 (pixel within 16), row = q*4+reg (co)
    // tile j: out row = r0 + (j>>2), cols (j&3)*16 + m16
#pragma unroll
    for (int i = 0; i < 4; ++i) {
        const int cobase = wy * 64 + i * 16 + q * 4;
#pragma unroll
        for (int reg = 0; reg < 4; ++reg) {
            float* op = out + ((size_t)b * COUT + (cobase + reg)) * (HW * HW) + r0 * HW + m16;
#pragma unroll
            for (int j = 0; j < 8; ++j)
                op[(j >> 2) * HW + (j & 3) * 16] = acc[i][j][reg];
        }
    }
}

extern "C" void kernel_launch(void* const* d_in, const int* in_sizes, int n_in,
                              void* d_out, int out_size, void* d_ws, size_t ws_size,
                              hipStream_t stream) {
    const float* x = (const float*)d_in[0];
    const float* s = (const float*)d_in[1];
    const float* w = (const float*)d_in[2];
    float* out = (float*)d_out;

    float* ws = (float*)d_ws;
    __bf16* wfull = (__bf16*)(ws + 70656);     // 18,874,368 B
    __bf16* zrow  = (__bf16*)(ws + 4789248);   // 36,864 B zero pool
    __bf16* xbf   = (__bf16*)(ws + 4798464);   // 33,554,432 B

    prep_kernel<<<1281, 256, 0, stream>>>(x, s, w, xbf, wfull, zrow);
    conv_mfma4<<<512, 256, 0, stream>>>(xbf, zrow, wfull, out);
}